// Round 1
// baseline (221.125 us; speedup 1.0000x reference)
//
#include <hip/hip_runtime.h>

#define B_TOTAL 2048
#define CAST    128
#define HDIM    256
#define INDIM   256
#define BM      8

__global__ __launch_bounds__(256) void k_init(int* slot_aid, int* stop) {
    int t = blockIdx.x * blockDim.x + threadIdx.x;
    if (t < B_TOTAL) { slot_aid[t] = -1; stop[t] = 0; }
}

__global__ __launch_bounds__(256) void k_fill(const int* __restrict__ batch_idxs,
                                              const int* __restrict__ actor_ids,
                                              const int* __restrict__ story_stop,
                                              int n_stop,
                                              int* slot_aid, int* slot_src, int* stop) {
    int t = blockIdx.x * blockDim.x + threadIdx.x;
    if (t < B_TOTAL) {
        int row = batch_idxs[t];
        int a = actor_ids[row];
        a = a < 0 ? 0 : (a > CAST - 1 ? CAST - 1 : a);
        slot_aid[row] = a;
        slot_src[row] = t;
    }
    if (t < n_stop) stop[story_stop[t]] = 1;
}

// One block = BM batch rows, 256 threads = one h column each.
// x and gathered-h rows staged in LDS (uniform broadcast reads in k-loop).
// Weights streamed as float4 per thread along k (row-sequential, L2-resident).
__global__ __launch_bounds__(256) void k_gru(
    const float* __restrict__ x, const int* __restrict__ batch_idxs,
    const int* __restrict__ actor_ids, const float* __restrict__ state,
    const float* __restrict__ w_ih, const float* __restrict__ w_hh,
    const float* __restrict__ b_ih, const float* __restrict__ b_hh,
    float* __restrict__ out_sel) {
    __shared__ float xs[BM][INDIM];
    __shared__ float ss[BM][HDIM];
    const int h  = threadIdx.x;
    const int b0 = blockIdx.x * BM;

    #pragma unroll
    for (int r = 0; r < BM; ++r) {
        int g  = b0 + r;
        int bi = batch_idxs[g];
        int a  = actor_ids[bi];
        a = a < 0 ? 0 : (a > CAST - 1 ? CAST - 1 : a);
        xs[r][h] = x[(size_t)g * INDIM + h];
        ss[r][h] = state[((size_t)bi * CAST + a) * HDIM + h];
    }
    __syncthreads();

    float air[BM], aiz[BM], ain[BM], ahr[BM], ahz[BM], ahn[BM];
    #pragma unroll
    for (int r = 0; r < BM; ++r) { air[r]=0.f; aiz[r]=0.f; ain[r]=0.f; ahr[r]=0.f; ahz[r]=0.f; ahn[r]=0.f; }

    const float4* __restrict__ wir_p = (const float4*)(w_ih + (size_t)h * INDIM);
    const float4* __restrict__ wiz_p = (const float4*)(w_ih + (size_t)(HDIM + h) * INDIM);
    const float4* __restrict__ win_p = (const float4*)(w_ih + (size_t)(2 * HDIM + h) * INDIM);
    const float4* __restrict__ whr_p = (const float4*)(w_hh + (size_t)h * HDIM);
    const float4* __restrict__ whz_p = (const float4*)(w_hh + (size_t)(HDIM + h) * HDIM);
    const float4* __restrict__ whn_p = (const float4*)(w_hh + (size_t)(2 * HDIM + h) * HDIM);

    for (int k4 = 0; k4 < INDIM / 4; ++k4) {
        float4 wir = wir_p[k4], wiz = wiz_p[k4], win = win_p[k4];
        float4 whr = whr_p[k4], whz = whz_p[k4], whn = whn_p[k4];
        #pragma unroll
        for (int r = 0; r < BM; ++r) {
            float4 xv = *(const float4*)(&xs[r][k4 * 4]);
            float4 sv = *(const float4*)(&ss[r][k4 * 4]);
            air[r] = fmaf(xv.w, wir.w, fmaf(xv.z, wir.z, fmaf(xv.y, wir.y, fmaf(xv.x, wir.x, air[r]))));
            aiz[r] = fmaf(xv.w, wiz.w, fmaf(xv.z, wiz.z, fmaf(xv.y, wiz.y, fmaf(xv.x, wiz.x, aiz[r]))));
            ain[r] = fmaf(xv.w, win.w, fmaf(xv.z, win.z, fmaf(xv.y, win.y, fmaf(xv.x, win.x, ain[r]))));
            ahr[r] = fmaf(sv.w, whr.w, fmaf(sv.z, whr.z, fmaf(sv.y, whr.y, fmaf(sv.x, whr.x, ahr[r]))));
            ahz[r] = fmaf(sv.w, whz.w, fmaf(sv.z, whz.z, fmaf(sv.y, whz.y, fmaf(sv.x, whz.x, ahz[r]))));
            ahn[r] = fmaf(sv.w, whn.w, fmaf(sv.z, whn.z, fmaf(sv.y, whn.y, fmaf(sv.x, whn.x, ahn[r]))));
        }
    }

    const float bir = b_ih[h], biz = b_ih[HDIM + h], bin = b_ih[2 * HDIM + h];
    const float bhr = b_hh[h], bhz = b_hh[HDIM + h], bhn = b_hh[2 * HDIM + h];

    #pragma unroll
    for (int r = 0; r < BM; ++r) {
        float ir = air[r] + bir, iz = aiz[r] + biz, inn = ain[r] + bin;
        float hr = ahr[r] + bhr, hz = ahz[r] + bhz, hn = ahn[r] + bhn;
        float rr = 1.f / (1.f + __expf(-(ir + hr)));
        float zz = 1.f / (1.f + __expf(-(iz + hz)));
        float nn = tanhf(inn + rr * hn);
        float hprev = ss[r][h];
        out_sel[(size_t)(b0 + r) * HDIM + h] = (1.f - zz) * nn + zz * hprev;
    }
}

// Grid-stride float4 copy state -> new_state with scatter override + stop-row zeroing.
__global__ __launch_bounds__(256) void k_fuse(const float* __restrict__ state,
                                              const float* __restrict__ new_sel,
                                              const int* __restrict__ slot_aid,
                                              const int* __restrict__ slot_src,
                                              const int* __restrict__ stop,
                                              float* __restrict__ out_state) {
    const long total  = (long)B_TOTAL * CAST * (HDIM / 4);   // float4 count
    const long stride = (long)gridDim.x * blockDim.x;
    for (long v = (long)blockIdx.x * blockDim.x + threadIdx.x; v < total; v += stride) {
        int h4 = (int)(v & (HDIM / 4 - 1));   // 0..63
        int c  = (int)((v >> 6) & (CAST - 1));
        int r  = (int)(v >> 13);
        float4 val;
        if (stop[r]) {
            val = make_float4(0.f, 0.f, 0.f, 0.f);
        } else if (slot_aid[r] == c) {
            val = ((const float4*)new_sel)[(size_t)slot_src[r] * (HDIM / 4) + h4];
        } else {
            val = ((const float4*)state)[v];
        }
        ((float4*)out_state)[v] = val;
    }
}

extern "C" void kernel_launch(void* const* d_in, const int* in_sizes, int n_in,
                              void* d_out, int out_size, void* d_ws, size_t ws_size,
                              hipStream_t stream) {
    const float* x          = (const float*)d_in[0];
    const int*   batch_idxs = (const int*)d_in[1];
    const int*   actor_ids  = (const int*)d_in[2];
    const int*   story_stop = (const int*)d_in[3];
    const float* state      = (const float*)d_in[4];
    const float* w_ih       = (const float*)d_in[5];
    const float* w_hh       = (const float*)d_in[6];
    const float* b_ih       = (const float*)d_in[7];
    const float* b_hh       = (const float*)d_in[8];
    const int    n_stop     = in_sizes[3];

    float* out_sel   = (float*)d_out;
    float* out_state = out_sel + (size_t)B_TOTAL * HDIM;

    int* slot_aid = (int*)d_ws;
    int* slot_src = slot_aid + B_TOTAL;
    int* stop     = slot_src + B_TOTAL;

    k_init<<<(B_TOTAL + 255) / 256, 256, 0, stream>>>(slot_aid, stop);
    k_fill<<<(B_TOTAL + 255) / 256, 256, 0, stream>>>(batch_idxs, actor_ids, story_stop,
                                                      n_stop, slot_aid, slot_src, stop);
    k_gru<<<B_TOTAL / BM, 256, 0, stream>>>(x, batch_idxs, actor_ids, state,
                                            w_ih, w_hh, b_ih, b_hh, out_sel);
    k_fuse<<<2048, 256, 0, stream>>>(state, out_sel, slot_aid, slot_src, stop, out_state);
}

// Round 2
// 170.472 us; speedup vs baseline: 1.2971x; 1.2971x over previous
//
#include <hip/hip_runtime.h>

#define B_TOTAL 2048
#define CAST    128
#define HDIM    256
#define INDIM   256
#define BM      8
#define GRU_BLOCKS  (B_TOTAL / BM)   // 256
#define COPY_BLOCKS 2048

// ---------------- tables init ----------------
__global__ __launch_bounds__(256) void k_init(int* slot_aid, int* stop) {
    int t = blockIdx.x * blockDim.x + threadIdx.x;
    if (t < B_TOTAL) { slot_aid[t] = -1; stop[t] = 0; }
}

// ---------------- fill tables + transpose weights ----------------
// blocks 0..7: fill slot_aid/stop. blocks 8..391: pack weights as
// wt[((k4*3 + gate)*256 + h)*4 + j] = w[(gate*256 + h)*256 + k4*4 + j]
__global__ __launch_bounds__(256) void k_prep(
    const int* __restrict__ batch_idxs, const int* __restrict__ actor_ids,
    const int* __restrict__ story_stop, int n_stop,
    const float* __restrict__ w_ih, const float* __restrict__ w_hh,
    int* slot_aid, int* stop, float* wtI, float* wtH) {
    const int h = threadIdx.x;
    if (blockIdx.x < 8) {
        int t = blockIdx.x * 256 + h;
        int row = batch_idxs[t];
        int a = actor_ids[row];
        a = a < 0 ? 0 : (a > CAST - 1 ? CAST - 1 : a);
        slot_aid[row] = a;
        if (t < n_stop) stop[story_stop[t]] = 1;
    } else {
        int id  = blockIdx.x - 8;          // 0..383
        int mat = id / 192;                // 0: w_ih, 1: w_hh
        int rem = id % 192;
        int g   = rem / 64;
        int k4  = rem % 64;
        const float* w = mat ? w_hh : w_ih;
        float*      wt = mat ? wtH  : wtI;
        float4 wv = *(const float4*)(w + ((size_t)(g * HDIM + h) * INDIM + k4 * 4));
        *(float4*)(wt + ((size_t)((k4 * 3 + g) * HDIM + h)) * 4) = wv;
    }
}

// ---------------- fused GRU + state copy ----------------
// blocks [0, GRU_BLOCKS): GRU for BM rows each; writes out_sel and scatters
//   its rows into out_state (unless stop).
// blocks [GRU_BLOCKS, GRU_BLOCKS+COPY_BLOCKS): float4 copy state->out_state,
//   zeroing stop rows, SKIPPING selected (slot_aid[r]==c) slots.
__global__ __launch_bounds__(256) void k_fused(
    const float* __restrict__ x, const int* __restrict__ batch_idxs,
    const int* __restrict__ actor_ids, const float* __restrict__ state,
    const float* __restrict__ wtI, const float* __restrict__ wtH,
    const float* __restrict__ b_ih, const float* __restrict__ b_hh,
    const int* __restrict__ slot_aid, const int* __restrict__ stop,
    float* __restrict__ out_sel, float* __restrict__ out_state) {
    __shared__ float xs[BM][INDIM];
    __shared__ float ss[BM][HDIM];
    const int h = threadIdx.x;

    if (blockIdx.x < GRU_BLOCKS) {
        const int b0 = blockIdx.x * BM;
        #pragma unroll
        for (int r = 0; r < BM; ++r) {
            int g  = b0 + r;
            int bi = batch_idxs[g];
            int a  = actor_ids[bi];
            a = a < 0 ? 0 : (a > CAST - 1 ? CAST - 1 : a);
            xs[r][h] = x[(size_t)g * INDIM + h];
            ss[r][h] = state[((size_t)bi * CAST + a) * HDIM + h];
        }
        __syncthreads();

        float air[BM], aiz[BM], ain[BM], ahr[BM], ahz[BM], ahn[BM];
        #pragma unroll
        for (int r = 0; r < BM; ++r) { air[r]=0.f; aiz[r]=0.f; ain[r]=0.f; ahr[r]=0.f; ahz[r]=0.f; ahn[r]=0.f; }

        const float4* __restrict__ wtI4 = (const float4*)wtI;
        const float4* __restrict__ wtH4 = (const float4*)wtH;

        for (int k4 = 0; k4 < INDIM / 4; ++k4) {
            float4 wir = wtI4[(k4 * 3 + 0) * HDIM + h];
            float4 wiz = wtI4[(k4 * 3 + 1) * HDIM + h];
            float4 win = wtI4[(k4 * 3 + 2) * HDIM + h];
            float4 whr = wtH4[(k4 * 3 + 0) * HDIM + h];
            float4 whz = wtH4[(k4 * 3 + 1) * HDIM + h];
            float4 whn = wtH4[(k4 * 3 + 2) * HDIM + h];
            #pragma unroll
            for (int r = 0; r < BM; ++r) {
                float4 xv = *(const float4*)(&xs[r][k4 * 4]);
                float4 sv = *(const float4*)(&ss[r][k4 * 4]);
                air[r] = fmaf(xv.w, wir.w, fmaf(xv.z, wir.z, fmaf(xv.y, wir.y, fmaf(xv.x, wir.x, air[r]))));
                aiz[r] = fmaf(xv.w, wiz.w, fmaf(xv.z, wiz.z, fmaf(xv.y, wiz.y, fmaf(xv.x, wiz.x, aiz[r]))));
                ain[r] = fmaf(xv.w, win.w, fmaf(xv.z, win.z, fmaf(xv.y, win.y, fmaf(xv.x, win.x, ain[r]))));
                ahr[r] = fmaf(sv.w, whr.w, fmaf(sv.z, whr.z, fmaf(sv.y, whr.y, fmaf(sv.x, whr.x, ahr[r]))));
                ahz[r] = fmaf(sv.w, whz.w, fmaf(sv.z, whz.z, fmaf(sv.y, whz.y, fmaf(sv.x, whz.x, ahz[r]))));
                ahn[r] = fmaf(sv.w, whn.w, fmaf(sv.z, whn.z, fmaf(sv.y, whn.y, fmaf(sv.x, whn.x, ahn[r]))));
            }
        }

        const float bir = b_ih[h], biz = b_ih[HDIM + h], bin = b_ih[2 * HDIM + h];
        const float bhr = b_hh[h], bhz = b_hh[HDIM + h], bhn = b_hh[2 * HDIM + h];

        #pragma unroll
        for (int r = 0; r < BM; ++r) {
            int g  = b0 + r;
            int bi = batch_idxs[g];
            int a  = actor_ids[bi];
            a = a < 0 ? 0 : (a > CAST - 1 ? CAST - 1 : a);
            float ir = air[r] + bir, iz = aiz[r] + biz, inn = ain[r] + bin;
            float hr = ahr[r] + bhr, hz = ahz[r] + bhz, hn = ahn[r] + bhn;
            float rr = 1.f / (1.f + __expf(-(ir + hr)));
            float zz = 1.f / (1.f + __expf(-(iz + hz)));
            float nn = tanhf(inn + rr * hn);
            float val = (1.f - zz) * nn + zz * ss[r][h];
            out_sel[(size_t)g * HDIM + h] = val;
            if (!stop[bi]) out_state[((size_t)bi * CAST + a) * HDIM + h] = val;
        }
    } else {
        const int  cb = blockIdx.x - GRU_BLOCKS;
        const long stride = (long)COPY_BLOCKS * 256;
        const long base = (long)cb * 256 + h;
        const float4* __restrict__ st4 = (const float4*)state;
        float4* __restrict__ out4 = (float4*)out_state;
        const float4 zero = make_float4(0.f, 0.f, 0.f, 0.f);
        // total float4 = 2048*128*64 = 16,777,216 = stride * 32 exactly
        #pragma unroll 2
        for (int it = 0; it < 32; it += 4) {
            long v0 = base + (long)(it + 0) * stride;
            long v1 = base + (long)(it + 1) * stride;
            long v2 = base + (long)(it + 2) * stride;
            long v3 = base + (long)(it + 3) * stride;
            float4 d0 = st4[v0], d1 = st4[v1], d2 = st4[v2], d3 = st4[v3];
            {
                int r = (int)(v0 >> 13), c = (int)((v0 >> 6) & (CAST - 1));
                if (stop[r]) out4[v0] = zero; else if (slot_aid[r] != c) out4[v0] = d0;
            }
            {
                int r = (int)(v1 >> 13), c = (int)((v1 >> 6) & (CAST - 1));
                if (stop[r]) out4[v1] = zero; else if (slot_aid[r] != c) out4[v1] = d1;
            }
            {
                int r = (int)(v2 >> 13), c = (int)((v2 >> 6) & (CAST - 1));
                if (stop[r]) out4[v2] = zero; else if (slot_aid[r] != c) out4[v2] = d2;
            }
            {
                int r = (int)(v3 >> 13), c = (int)((v3 >> 6) & (CAST - 1));
                if (stop[r]) out4[v3] = zero; else if (slot_aid[r] != c) out4[v3] = d3;
            }
        }
    }
}

extern "C" void kernel_launch(void* const* d_in, const int* in_sizes, int n_in,
                              void* d_out, int out_size, void* d_ws, size_t ws_size,
                              hipStream_t stream) {
    const float* x          = (const float*)d_in[0];
    const int*   batch_idxs = (const int*)d_in[1];
    const int*   actor_ids  = (const int*)d_in[2];
    const int*   story_stop = (const int*)d_in[3];
    const float* state      = (const float*)d_in[4];
    const float* w_ih       = (const float*)d_in[5];
    const float* w_hh       = (const float*)d_in[6];
    const float* b_ih       = (const float*)d_in[7];
    const float* b_hh       = (const float*)d_in[8];
    const int    n_stop     = in_sizes[3];

    float* out_sel   = (float*)d_out;
    float* out_state = out_sel + (size_t)B_TOTAL * HDIM;

    int*   slot_aid = (int*)d_ws;
    int*   stop     = slot_aid + B_TOTAL;
    float* wtI      = (float*)((char*)d_ws + 16384);          // 16B-aligned
    float* wtH      = wtI + (size_t)3 * HDIM * INDIM;         // 768 KB each

    k_init<<<(B_TOTAL + 255) / 256, 256, 0, stream>>>(slot_aid, stop);
    k_prep<<<8 + 384, 256, 0, stream>>>(batch_idxs, actor_ids, story_stop, n_stop,
                                        w_ih, w_hh, slot_aid, stop, wtI, wtH);
    k_fused<<<GRU_BLOCKS + COPY_BLOCKS, 256, 0, stream>>>(
        x, batch_idxs, actor_ids, state, wtI, wtH, b_ih, b_hh,
        slot_aid, stop, out_sel, out_state);
}